// Round 1
// 137.237 us; speedup vs baseline: 1.0277x; 1.0277x over previous
//
#include <hip/hip_runtime.h>

#define H 360
#define W 720
#define NB 8
#define XC 3
#define YC 10
#define TX 240
#define TY 36
#define BPB (XC*YC)             // 30 blocks per batch
#define WR 52                   // window rows: gi = by-8+r, r in 0..51
#define LST 260                 // LDS row stride (floats): 256 cols + 4 pad
#define LSZ (WR*LST)            // one window buffer (floats)
#define DTS 600.0f
#define REARTH 6371000.0f
#define D2R 0.017453292519943295f

#define NQ1 (WR*64)             // 3328 preamble quads
#define NHALO 1168              // rows{0..7,44..51}x64 + rows 8..43 x quads{0,1,62,63}
#define NGROUPS 5               // 5 groups x 4 substeps = 20 steps
#define FLAG_STRIDE 32          // 128 B per flag line

// LLC-coherent 8B load/store (agent-scope relaxed atomic -> dwordx2 sc1)
static __device__ __forceinline__ float2 ldc8(const float* p) {
    unsigned long long u = __hip_atomic_load((const unsigned long long*)p,
                                             __ATOMIC_RELAXED, __HIP_MEMORY_SCOPE_AGENT);
    return __builtin_bit_cast(float2, u);
}
static __device__ __forceinline__ void stc8(float* p, float2 v) {
    __hip_atomic_store((unsigned long long*)p, __builtin_bit_cast(unsigned long long, v),
                       __ATOMIC_RELAXED, __HIP_MEMORY_SCOPE_AGENT);
}

// DPP wave-wide lane shifts on the VALU pipe.
// Replaces __shfl_up/__shfl_down(,1) which compile to ds_bpermute (LDS pipe,
// ~35-cy round trip on the substep critical chain). bound_ctrl=1: shifted-in
// lanes read 0 — lands only in window cols 0/255 (degraded halo, unconsumed).
static __device__ __forceinline__ float dpp_up1(float x) {   // lane i <- lane i-1
    return __builtin_bit_cast(float, __builtin_amdgcn_update_dpp(
        0, __builtin_bit_cast(int, x), 0x138 /*wave_shr:1*/, 0xF, 0xF, true));
}
static __device__ __forceinline__ float dpp_dn1(float x) {   // lane i <- lane i+1
    return __builtin_bit_cast(float, __builtin_amdgcn_update_dpp(
        0, __builtin_bit_cast(int, x), 0x130 /*wave_shl:1*/, 0xF, 0xF, true));
}

__global__ __launch_bounds__(512, 2) void ocean_persist(
    const float* __restrict__ Tin, const float* __restrict__ ug,
    const float* __restrict__ vg, const float* __restrict__ lat,
    const float* __restrict__ lon, const float* __restrict__ mask,
    float* __restrict__ out, float* __restrict__ wsf, int* __restrict__ flags)
{
    // Double-buffered window: stage1 reads buf p, stage2 writes buf p^1 ->
    // one barrier per substep instead of two. 108 KB LDS; grid already caps
    // residency at 1 block/CU so no occupancy cost.
    __shared__ float sT[2 * LSZ];

    const int tid = threadIdx.x;
    const int b  = blockIdx.z;
    const int bx = blockIdx.x * TX;
    const int by = blockIdx.y * TY;
    const int plane = H * W;

    const float dlat = lat[1] - lat[0];               // -0.5
    const float dy   = REARTH * D2R * fabsf(dlat);
    const float sgn  = (dlat > 0.f) ? 1.f : -1.f;
    const float dlon = lon[1] - lon[0];
    const float i2dy = 0.5f / dy, i1dy = 1.f / dy;

    const float* Tb = Tin + b * plane;
    const float* ub = ug  + b * plane;
    const float* vb = vg  + b * plane;
    float* outb = out + b * plane;
    float* wsb  = wsf + b * plane;

    int* bflags = flags + b * BPB * FLAG_STRIDE;
    int* myflag = bflags + (blockIdx.y * XC + blockIdx.x) * FLAG_STRIDE;

    // ---------- strip mapping: wave = row-group ----------
    const int cq = tid & 63;             // col quad 0..63 (window cols 0..255)
    const int rg = tid >> 6;             // row group 0..7 (== wave id)
    const int c0 = cq << 2;
    const int a  = 1 + 6 * rg;           // first h row (sT row index); h rows a..a+7
    const int gj0 = (bx - 8 + c0 + W) % W;
    const bool hlzb = (gj0 == 0);            // filter zero-pad left of gj=0
    const bool hrzb = (gj0 + 3 == W - 1);    // filter zero-pad right of gj=W-1
    const bool topB = (blockIdx.y == 0), botB = (blockIdx.y == YC - 1);

    // ---------- bake invariants ----------
    int goff1[7], lds1o[7];              // preamble quads
    #pragma unroll
    for (int k = 0; k < 7; ++k) {
        const int q = tid + 512 * k;
        if (q < NQ1) {
            const int r = q >> 6, cc0 = (q & 63) << 2;
            int gi = by - 8 + r; gi = min(max(gi, 0), H - 1);
            const int gj = (bx - 8 + cc0 + W) % W;
            goff1[k] = gi * W + gj;
            lds1o[k] = r * LST + cc0;
        } else goff1[k] = -1;
    }

    int hgo[3], hlo[3];                  // halo import quads (3/thread)
    #pragma unroll
    for (int t = 0; t < 3; ++t) {
        const int q = tid + 512 * t;
        if (q < NHALO) {
            int r, cc0;
            if (q < 1024) { const int ri = q >> 6; r = (ri < 8) ? ri : 36 + ri; cc0 = (q & 63) << 2; }
            else { const int u = q - 1024; r = 8 + (u >> 2); const int qi = u & 3;
                   cc0 = (qi < 2) ? (qi << 2) : (248 + ((qi - 2) << 2)); }
            int gi = by - 8 + r; gi = min(max(gi, 0), H - 1);
            const int gj = (bx - 8 + cc0 + W) % W;
            hgo[t] = gi * W + gj;
            hlo[t] = r * LST + cc0;
        } else hgo[t] = -1;
    }

    // advection coeffs for own 8 h rows (wrapped gj -> halo cols evolve truly)
    float cuA[8][4], cvA[8][4];
    unsigned domm = 0;
    #pragma unroll
    for (int j = 0; j < 8; ++j) {
        #pragma unroll
        for (int t = 0; t < 4; ++t) { cuA[j][t] = 0.f; cvA[j][t] = 0.f; }
        const int gi = by - 8 + a + j;
        if ((unsigned)gi < H) {
            const float dxv  = REARTH * D2R * dlon * cosf(lat[gi] * D2R);
            const float rdx2 = 0.5f / dxv;
            const float ivy  = (gi == 0 || gi == H - 1) ? i1dy : i2dy;
            #pragma unroll
            for (int t = 0; t < 4; ++t) {
                const int off = gi * W + gj0 + t;
                const float mk = mask[off];
                cuA[j][t] = -DTS * mk * ub[off] * rdx2;
                cvA[j][t] = -DTS * mk * vb[off] * sgn * ivy;
            }
            domm |= 1u << j;
        }
    }

    // out rows n = 2+6rg+i, i = 0..5
    float m16A[6][4];
    int o3A[6];
    unsigned outm = 0, tilem = 0, ringm = 0;
    #pragma unroll
    for (int i = 0; i < 6; ++i) {
        const int n = 2 + 6 * rg + i;
        const int gi = by - 8 + n;
        o3A[i] = 0;
        #pragma unroll
        for (int t = 0; t < 4; ++t)
            m16A[i][t] = ((unsigned)gi < H) ? mask[gi * W + gj0 + t] * (1.f / 16.f) : 0.f;
        if ((unsigned)gi < H) outm |= 1u << i;    // write sT (in-domain rows only)
        const bool inTile = (n >= 8 && n <= 43 && cq >= 2 && cq <= 61);
        if (inTile) {
            o3A[i] = gi * W + bx + c0 - 8;
            tilem |= 1u << i;
            if (n <= 15 || n >= 36 || cq <= 3 || cq >= 60) ringm |= 1u << i;
        }
    }

    // neighbor flag pointers (8-neighborhood; x wraps, y clamps to self)
    const int* nbrF = myflag;
    if (tid < 8) {
        int dyn, dxn;
        if (tid < 3)      { dyn = -1; dxn = tid - 1; }
        else if (tid == 3){ dyn = 0;  dxn = -1; }
        else if (tid == 4){ dyn = 0;  dxn = 1; }
        else              { dyn = 1;  dxn = tid - 6; }
        const int ny = (int)blockIdx.y + dyn;
        const int nx = ((int)blockIdx.x + dxn + XC) % XC;
        if (ny >= 0 && ny < YC) nbrF = bflags + (ny * XC + nx) * FLAG_STRIDE;
    }

    // ---------- preamble: full window -> BOTH buffers ----------
    // (buf1's never-rewritten halo rows 0,1,50,51 must hold finite values;
    //  they are only ever consumed into the degraded-validity region.)
    #pragma unroll
    for (int k = 0; k < 7; ++k)
        if (goff1[k] >= 0) {
            const float4 v = *(const float4*)(Tb + goff1[k]);
            *(float4*)(sT + lds1o[k])       = v;
            *(float4*)(sT + LSZ + lds1o[k]) = v;
        }
    __syncthreads();

    // ---------- one substep: read buf p, write buf p^1, ONE barrier ----------
    auto substep = [&](int p, bool finalOut, float* ring) {
        const float* cur = sT + p * LSZ;
        float* nxt = sT + (p ^ 1) * LSZ;
        float4 hA[8];
        float4 m1 = *(const float4*)(cur + (a - 1) * LST + c0);
        float4 cc = *(const float4*)(cur + a * LST + c0);
        #pragma unroll
        for (int j = 0; j < 8; ++j) {
            const float4 vD = *(const float4*)(cur + (a + j + 1) * LST + c0);
            const float tl = dpp_up1(cc.w);    // 0 only at cq=0 -> col 0 (unconsumed)
            const float tr = dpp_dn1(cc.x);    // 0 only at cq=63 -> col 255
            const bool dj = (domm >> j) & 1;
            float4 o;
            o.x = (dj ? cc.x : 0.f) + cuA[j][0]*(cc.y - tl)   + cvA[j][0]*(vD.x - m1.x);
            o.y = (dj ? cc.y : 0.f) + cuA[j][1]*(cc.z - cc.x) + cvA[j][1]*(vD.y - m1.y);
            o.z = (dj ? cc.z : 0.f) + cuA[j][2]*(cc.w - cc.y) + cvA[j][2]*(vD.z - m1.z);
            o.w = (dj ? cc.w : 0.f) + cuA[j][3]*(tr   - cc.z) + cvA[j][3]*(vD.w - m1.w);
            float hl = dpp_up1(o.w);
            float hr = dpp_dn1(o.x);
            if (hlzb) hl = 0.f;
            if (hrzb) hr = 0.f;
            hA[j].x = hl  + 2.f * o.x + o.y;
            hA[j].y = o.x + 2.f * o.y + o.z;
            hA[j].z = o.y + 2.f * o.z + o.w;
            hA[j].w = o.z + 2.f * o.w + hr;
            m1 = cc; cc = vD;
        }
        // no mid-substep barrier: stage2 writes the OTHER buffer
        #pragma unroll
        for (int i = 0; i < 6; ++i) {
            const float4 hm = hA[i], hc = hA[i + 1], hp = hA[i + 2];
            float4 o;
            o.x = (hm.x + 2.f * hc.x + hp.x) * m16A[i][0];
            o.y = (hm.y + 2.f * hc.y + hp.y) * m16A[i][1];
            o.z = (hm.z + 2.f * hc.z + hp.z) * m16A[i][2];
            o.w = (hm.w + 2.f * hc.w + hp.w) * m16A[i][3];
            if (!finalOut) {
                if ((outm >> i) & 1)
                    *(float4*)(nxt + (2 + 6 * rg + i) * LST + c0) = o;
                // clamp-replica patches (unique writers: edge rows suppressed above)
                if (topB && rg == 1 && i == 0) *(float4*)(nxt + 7  * LST + c0) = o;  // row7 <- n=8
                if (botB && rg == 6 && i == 5) *(float4*)(nxt + 44 * LST + c0) = o;  // row44 <- n=43
            } else if ((tilem >> i) & 1) {
                *(float4*)(outb + o3A[i]) = o;
            }
            if (ring && ((ringm >> i) & 1)) {
                float2 lo; lo.x = o.x; lo.y = o.y;
                float2 hi; hi.x = o.z; hi.y = o.w;
                stc8(ring + o3A[i], lo);
                stc8(ring + o3A[i] + 2, hi);
            }
        }
        __syncthreads();
    };

    // ---------- 5 groups x 4 substeps ----------
    // Parity: substeps read 0,1,0,1 -> group always ends with data in buf0,
    // and the halo import always lands in buf0.
    #pragma unroll 1
    for (int g = 0; g < NGROUPS; ++g) {
        if (g) {
            __syncthreads();   // drains ring stores (per-wave vmcnt0 before s_barrier)
            if (tid == 0)
                __hip_atomic_store(myflag, g, __ATOMIC_RELAXED, __HIP_MEMORY_SCOPE_AGENT);
            if (tid < 64) {    // wave 0, lanes 0..7 poll the 8 neighbors
                long long t0 = (long long)clock64();
                for (;;) {
                    const int v = (tid < 8)
                        ? __hip_atomic_load(nbrF, __ATOMIC_RELAXED, __HIP_MEMORY_SCOPE_AGENT)
                        : 0x7fffffff;
                    if (__all(v >= g)) break;
                    __builtin_amdgcn_s_sleep(1);
                    if ((long long)clock64() - t0 > 200000000LL) break;  // no-hang bailout
                }
            }
            __syncthreads();
            // halo import (depth 8) from ring(g-1): g-1 even -> outb, odd -> wsb
            const float* prev = ((g - 1) & 1) ? wsb : outb;
            #pragma unroll
            for (int t = 0; t < 3; ++t) {
                if (hgo[t] >= 0) {
                    const float2 lo = ldc8(prev + hgo[t]);
                    const float2 hi = ldc8(prev + hgo[t] + 2);
                    float4 v; v.x = lo.x; v.y = lo.y; v.z = hi.x; v.w = hi.y;
                    *(float4*)(sT + hlo[t]) = v;   // buf0 = current data buffer
                }
            }
            __syncthreads();
        }
        const bool lastG = (g == NGROUPS - 1);
        float* ring = lastG ? nullptr : ((g & 1) ? wsb : outb);   // ring(g)
        substep(0, false, nullptr);
        substep(1, false, nullptr);
        substep(0, false, nullptr);
        substep(1, lastG, ring);            // 4th substep: export ring / final tile
    }
}

extern "C" void kernel_launch(void* const* d_in, const int* in_sizes, int n_in,
                              void* d_out, int out_size, void* d_ws, size_t ws_size,
                              hipStream_t stream)
{
    const float* T    = (const float*)d_in[0];
    const float* ug   = (const float*)d_in[1];
    const float* vg   = (const float*)d_in[2];
    const float* lat  = (const float*)d_in[3];
    const float* lon  = (const float*)d_in[4];
    const float* mask = (const float*)d_in[5];
    float* out = (float*)d_out;

    int*   flags = (int*)d_ws;                        // 8 x 30 flags @ 128 B
    float* wsf   = (float*)((char*)d_ws + 65536);     // odd-group ring buffer

    hipMemsetAsync(d_ws, 0, 65536, stream);

    ocean_persist<<<dim3(XC, YC, NB), dim3(512), 0, stream>>>(
        T, ug, vg, lat, lon, mask, out, wsf, flags);
}

// Round 2
// 137.102 us; speedup vs baseline: 1.0287x; 1.0010x over previous
//
#include <hip/hip_runtime.h>

#define H 360
#define W 720
#define NB 8
#define XC 3
#define YC 10
#define TX 240
#define TY 36
#define BPB (XC*YC)             // 30 blocks per batch
#define WR 52                   // window rows: gi = by-8+r, r in 0..51
#define LST 260                 // LDS row stride (floats): 256 cols + 4 pad
#define LSZ (WR*LST)            // one window buffer (floats)
#define DTS 600.0f
#define REARTH 6371000.0f
#define D2R 0.017453292519943295f

#define NQ1 (WR*64)             // 3328 preamble quads
#define NHALO 1168              // rows{0..7,44..51}x64 + rows 8..43 x quads{0,1,62,63}
#define NGROUPS 5               // 5 groups x 4 substeps = 20 steps
#define FLAG_STRIDE 32          // 128 B per flag line

// 16 waves x 3-row output pitch (was 8 waves x 6): same WR=52 window,
// same tile, same ring/flag protocol; doubles waves/SIMD from 2 to 4.

// LLC-coherent 8B load/store (agent-scope relaxed atomic -> dwordx2 sc1)
static __device__ __forceinline__ float2 ldc8(const float* p) {
    unsigned long long u = __hip_atomic_load((const unsigned long long*)p,
                                             __ATOMIC_RELAXED, __HIP_MEMORY_SCOPE_AGENT);
    return __builtin_bit_cast(float2, u);
}
static __device__ __forceinline__ void stc8(float* p, float2 v) {
    __hip_atomic_store((unsigned long long*)p, __builtin_bit_cast(unsigned long long, v),
                       __ATOMIC_RELAXED, __HIP_MEMORY_SCOPE_AGENT);
}

// DPP wave-wide lane shifts on the VALU pipe (bound_ctrl=1: shifted-in lanes
// read 0 — lands only in window cols 0/255, the unconsumed degraded halo).
static __device__ __forceinline__ float dpp_up1(float x) {   // lane i <- lane i-1
    return __builtin_bit_cast(float, __builtin_amdgcn_update_dpp(
        0, __builtin_bit_cast(int, x), 0x138 /*wave_shr:1*/, 0xF, 0xF, true));
}
static __device__ __forceinline__ float dpp_dn1(float x) {   // lane i <- lane i+1
    return __builtin_bit_cast(float, __builtin_amdgcn_update_dpp(
        0, __builtin_bit_cast(int, x), 0x130 /*wave_shl:1*/, 0xF, 0xF, true));
}

__global__ __launch_bounds__(1024, 4) void ocean_persist(
    const float* __restrict__ Tin, const float* __restrict__ ug,
    const float* __restrict__ vg, const float* __restrict__ lat,
    const float* __restrict__ lon, const float* __restrict__ mask,
    float* __restrict__ out, float* __restrict__ wsf, int* __restrict__ flags)
{
    // Double-buffered window: stage1 reads buf p, stage2 writes buf p^1 ->
    // one barrier per substep. 108 KB LDS, 1 block/CU (grid caps residency).
    __shared__ float sT[2 * LSZ];

    const int tid = threadIdx.x;
    const int b  = blockIdx.z;
    const int bx = blockIdx.x * TX;
    const int by = blockIdx.y * TY;
    const int plane = H * W;

    const float dlat = lat[1] - lat[0];               // -0.5
    const float dy   = REARTH * D2R * fabsf(dlat);
    const float sgn  = (dlat > 0.f) ? 1.f : -1.f;
    const float dlon = lon[1] - lon[0];
    const float i2dy = 0.5f / dy, i1dy = 1.f / dy;

    const float* Tb = Tin + b * plane;
    const float* ub = ug  + b * plane;
    const float* vb = vg  + b * plane;
    float* outb = out + b * plane;
    float* wsb  = wsf + b * plane;

    int* bflags = flags + b * BPB * FLAG_STRIDE;
    int* myflag = bflags + (blockIdx.y * XC + blockIdx.x) * FLAG_STRIDE;

    // ---------- strip mapping: wave = 3-row group ----------
    const int cq = tid & 63;             // col quad 0..63 (window cols 0..255)
    const int rg = tid >> 6;             // row group 0..15 (== wave id)
    const int c0 = cq << 2;
    const int a  = 1 + 3 * rg;           // first h row; h rows a..a+4 (j<5)
    const int gj0 = (bx - 8 + c0 + W) % W;
    const bool hlzb = (gj0 == 0);            // filter zero-pad left of gj=0
    const bool hrzb = (gj0 + 3 == W - 1);    // filter zero-pad right of gj=W-1
    const bool topB = (blockIdx.y == 0), botB = (blockIdx.y == YC - 1);

    // ---------- bake invariants ----------
    int goff1[4], lds1o[4];              // preamble quads (1024-thread stride)
    #pragma unroll
    for (int k = 0; k < 4; ++k) {
        const int q = tid + 1024 * k;
        if (q < NQ1) {
            const int r = q >> 6, cc0 = (q & 63) << 2;
            int gi = by - 8 + r; gi = min(max(gi, 0), H - 1);
            const int gj = (bx - 8 + cc0 + W) % W;
            goff1[k] = gi * W + gj;
            lds1o[k] = r * LST + cc0;
        } else goff1[k] = -1;
    }

    int hgo[2], hlo[2];                  // halo import quads (2/thread)
    #pragma unroll
    for (int t = 0; t < 2; ++t) {
        const int q = tid + 1024 * t;
        if (q < NHALO) {
            int r, cc0;
            if (q < 1024) { const int ri = q >> 6; r = (ri < 8) ? ri : 36 + ri; cc0 = (q & 63) << 2; }
            else { const int u = q - 1024; r = 8 + (u >> 2); const int qi = u & 3;
                   cc0 = (qi < 2) ? (qi << 2) : (248 + ((qi - 2) << 2)); }
            int gi = by - 8 + r; gi = min(max(gi, 0), H - 1);
            const int gj = (bx - 8 + cc0 + W) % W;
            hgo[t] = gi * W + gj;
            hlo[t] = r * LST + cc0;
        } else hgo[t] = -1;
    }

    // advection coeffs for own 5 h rows (wrapped gj -> halo cols evolve truly)
    float cuA[5][4], cvA[5][4];
    unsigned domm = 0;
    #pragma unroll
    for (int j = 0; j < 5; ++j) {
        #pragma unroll
        for (int t = 0; t < 4; ++t) { cuA[j][t] = 0.f; cvA[j][t] = 0.f; }
        const int gi = by - 8 + a + j;
        if ((unsigned)gi < H) {
            const float dxv  = REARTH * D2R * dlon * cosf(lat[gi] * D2R);
            const float rdx2 = 0.5f / dxv;
            const float ivy  = (gi == 0 || gi == H - 1) ? i1dy : i2dy;
            #pragma unroll
            for (int t = 0; t < 4; ++t) {
                const int off = gi * W + gj0 + t;
                const float mk = mask[off];
                cuA[j][t] = -DTS * mk * ub[off] * rdx2;
                cvA[j][t] = -DTS * mk * vb[off] * sgn * ivy;
            }
            domm |= 1u << j;
        }
    }

    // out rows n = 2+3rg+i, i = 0..2
    float m16A[3][4];
    int o3A[3];
    unsigned outm = 0, tilem = 0, ringm = 0;
    #pragma unroll
    for (int i = 0; i < 3; ++i) {
        const int n = 2 + 3 * rg + i;
        const int gi = by - 8 + n;
        o3A[i] = 0;
        #pragma unroll
        for (int t = 0; t < 4; ++t)
            m16A[i][t] = ((unsigned)gi < H) ? mask[gi * W + gj0 + t] * (1.f / 16.f) : 0.f;
        if ((unsigned)gi < H) outm |= 1u << i;    // write sT (in-domain rows only)
        const bool inTile = (n >= 8 && n <= 43 && cq >= 2 && cq <= 61);
        if (inTile) {
            o3A[i] = gi * W + bx + c0 - 8;
            tilem |= 1u << i;
            if (n <= 15 || n >= 36 || cq <= 3 || cq >= 60) ringm |= 1u << i;
        }
    }

    // neighbor flag pointers (8-neighborhood; x wraps, y clamps to self)
    const int* nbrF = myflag;
    if (tid < 8) {
        int dyn, dxn;
        if (tid < 3)      { dyn = -1; dxn = tid - 1; }
        else if (tid == 3){ dyn = 0;  dxn = -1; }
        else if (tid == 4){ dyn = 0;  dxn = 1; }
        else              { dyn = 1;  dxn = tid - 6; }
        const int ny = (int)blockIdx.y + dyn;
        const int nx = ((int)blockIdx.x + dxn + XC) % XC;
        if (ny >= 0 && ny < YC) nbrF = bflags + (ny * XC + nx) * FLAG_STRIDE;
    }

    // ---------- preamble: full window -> BOTH buffers ----------
    // (buf1's never-rewritten halo rows 0,1,50,51 must hold finite values;
    //  they are only ever consumed into the degraded-validity region.)
    #pragma unroll
    for (int k = 0; k < 4; ++k)
        if (goff1[k] >= 0) {
            const float4 v = *(const float4*)(Tb + goff1[k]);
            *(float4*)(sT + lds1o[k])       = v;
            *(float4*)(sT + LSZ + lds1o[k]) = v;
        }
    __syncthreads();

    // ---------- one substep: read buf p, write buf p^1, ONE barrier ----------
    auto substep = [&](int p, bool finalOut, float* ring) {
        const float* cur = sT + p * LSZ;
        float* nxt = sT + (p ^ 1) * LSZ;
        float4 hA[5];
        float4 m1 = *(const float4*)(cur + (a - 1) * LST + c0);
        float4 cc = *(const float4*)(cur + a * LST + c0);
        #pragma unroll
        for (int j = 0; j < 5; ++j) {
            const float4 vD = *(const float4*)(cur + (a + j + 1) * LST + c0);
            const float tl = dpp_up1(cc.w);    // 0 only at cq=0 -> col 0 (unconsumed)
            const float tr = dpp_dn1(cc.x);    // 0 only at cq=63 -> col 255
            const bool dj = (domm >> j) & 1;
            float4 o;
            o.x = (dj ? cc.x : 0.f) + cuA[j][0]*(cc.y - tl)   + cvA[j][0]*(vD.x - m1.x);
            o.y = (dj ? cc.y : 0.f) + cuA[j][1]*(cc.z - cc.x) + cvA[j][1]*(vD.y - m1.y);
            o.z = (dj ? cc.z : 0.f) + cuA[j][2]*(cc.w - cc.y) + cvA[j][2]*(vD.z - m1.z);
            o.w = (dj ? cc.w : 0.f) + cuA[j][3]*(tr   - cc.z) + cvA[j][3]*(vD.w - m1.w);
            float hl = dpp_up1(o.w);
            float hr = dpp_dn1(o.x);
            if (hlzb) hl = 0.f;
            if (hrzb) hr = 0.f;
            hA[j].x = hl  + 2.f * o.x + o.y;
            hA[j].y = o.x + 2.f * o.y + o.z;
            hA[j].z = o.y + 2.f * o.z + o.w;
            hA[j].w = o.z + 2.f * o.w + hr;
            m1 = cc; cc = vD;
        }
        // no mid-substep barrier: stage2 writes the OTHER buffer
        #pragma unroll
        for (int i = 0; i < 3; ++i) {
            const float4 hm = hA[i], hc = hA[i + 1], hp = hA[i + 2];
            float4 o;
            o.x = (hm.x + 2.f * hc.x + hp.x) * m16A[i][0];
            o.y = (hm.y + 2.f * hc.y + hp.y) * m16A[i][1];
            o.z = (hm.z + 2.f * hc.z + hp.z) * m16A[i][2];
            o.w = (hm.w + 2.f * hc.w + hp.w) * m16A[i][3];
            if (!finalOut) {
                if ((outm >> i) & 1)
                    *(float4*)(nxt + (2 + 3 * rg + i) * LST + c0) = o;
                // clamp-replica patches (unique writers: edge rows suppressed above)
                if (topB && rg == 2  && i == 0) *(float4*)(nxt + 7  * LST + c0) = o;  // row7 <- n=8
                if (botB && rg == 13 && i == 2) *(float4*)(nxt + 44 * LST + c0) = o;  // row44 <- n=43
            } else if ((tilem >> i) & 1) {
                *(float4*)(outb + o3A[i]) = o;
            }
            if (ring && ((ringm >> i) & 1)) {
                float2 lo; lo.x = o.x; lo.y = o.y;
                float2 hi; hi.x = o.z; hi.y = o.w;
                stc8(ring + o3A[i], lo);
                stc8(ring + o3A[i] + 2, hi);
            }
        }
        __syncthreads();
    };

    // ---------- 5 groups x 4 substeps ----------
    // Parity: substeps read 0,1,0,1 -> group always ends with data in buf0,
    // and the halo import always lands in buf0.
    #pragma unroll 1
    for (int g = 0; g < NGROUPS; ++g) {
        if (g) {
            __syncthreads();   // drains ring stores (per-wave vmcnt0 before s_barrier)
            if (tid == 0)
                __hip_atomic_store(myflag, g, __ATOMIC_RELAXED, __HIP_MEMORY_SCOPE_AGENT);
            if (tid < 64) {    // wave 0, lanes 0..7 poll the 8 neighbors
                long long t0 = (long long)clock64();
                for (;;) {
                    const int v = (tid < 8)
                        ? __hip_atomic_load(nbrF, __ATOMIC_RELAXED, __HIP_MEMORY_SCOPE_AGENT)
                        : 0x7fffffff;
                    if (__all(v >= g)) break;
                    __builtin_amdgcn_s_sleep(1);
                    if ((long long)clock64() - t0 > 200000000LL) break;  // no-hang bailout
                }
            }
            __syncthreads();
            // halo import (depth 8) from ring(g-1): g-1 even -> outb, odd -> wsb
            const float* prev = ((g - 1) & 1) ? wsb : outb;
            #pragma unroll
            for (int t = 0; t < 2; ++t) {
                if (hgo[t] >= 0) {
                    const float2 lo = ldc8(prev + hgo[t]);
                    const float2 hi = ldc8(prev + hgo[t] + 2);
                    float4 v; v.x = lo.x; v.y = lo.y; v.z = hi.x; v.w = hi.y;
                    *(float4*)(sT + hlo[t]) = v;   // buf0 = current data buffer
                }
            }
            __syncthreads();
        }
        const bool lastG = (g == NGROUPS - 1);
        float* ring = lastG ? nullptr : ((g & 1) ? wsb : outb);   // ring(g)
        substep(0, false, nullptr);
        substep(1, false, nullptr);
        substep(0, false, nullptr);
        substep(1, lastG, ring);            // 4th substep: export ring / final tile
    }
}

extern "C" void kernel_launch(void* const* d_in, const int* in_sizes, int n_in,
                              void* d_out, int out_size, void* d_ws, size_t ws_size,
                              hipStream_t stream)
{
    const float* T    = (const float*)d_in[0];
    const float* ug   = (const float*)d_in[1];
    const float* vg   = (const float*)d_in[2];
    const float* lat  = (const float*)d_in[3];
    const float* lon  = (const float*)d_in[4];
    const float* mask = (const float*)d_in[5];
    float* out = (float*)d_out;

    int*   flags = (int*)d_ws;                        // 8 x 30 flags @ 128 B
    float* wsf   = (float*)((char*)d_ws + 65536);     // odd-group ring buffer

    hipMemsetAsync(d_ws, 0, 65536, stream);

    ocean_persist<<<dim3(XC, YC, NB), dim3(1024), 0, stream>>>(
        T, ug, vg, lat, lon, mask, out, wsf, flags);
}